// Round 1
// baseline (1479.107 us; speedup 1.0000x reference)
//
#include <hip/hip_runtime.h>
#include <hip/hip_bf16.h>
#include <math.h>

// Problem constants
#define Bsz 2
#define Cseq 512
#define Dm 512
#define NHd 8
#define HDm 64
#define Eexp 8
#define Ktop 2
#define FFm 2048
#define Lnum 2
#define Ttok (Bsz*Cseq)          // 1024
#define TD (Ttok*Dm)             // 524288

// ---------------- GEMM tile config ----------------
#define GBM 128
#define GBN 64
#define GBK 16

// Shared tiled-GEMM body. arow_s[GBM] holds the A-matrix row index for each
// tile row (-1 => invalid row: loads as zero, store skipped). C row for tile
// row r is cRowBase + r.
template<int ACT>
__device__ __forceinline__ void gemm_body(
    const float* __restrict__ A, int lda,
    const float* __restrict__ Bm, int ldb,
    const float* __restrict__ bias,
    float* __restrict__ C, int ldc,
    int n0, int K, int cRowBase,
    const int* __restrict__ arow_s)
{
  __shared__ float As[GBK][GBM + 4];
  __shared__ float Bs[GBK][GBN + 4];
  const int tid = threadIdx.x;
  const int tx = tid & 15;        // col group (4 cols)
  const int ty = tid >> 4;        // row group (8 rows)
  const int lrA = tid >> 2;       // A-load row (and +64)
  const int kcA = (tid & 3) << 2; // A-load k offset
  const int rB = tid >> 4;        // B-load row
  const int cB = (tid & 15) << 2; // B-load col

  float acc[8][4] = {};

  for (int k0 = 0; k0 < K; k0 += GBK) {
    #pragma unroll
    for (int h = 0; h < 2; ++h) {
      int r = lrA + h * 64;
      int ar = arow_s[r];
      float4 av = make_float4(0.f, 0.f, 0.f, 0.f);
      if (ar >= 0)
        av = *reinterpret_cast<const float4*>(&A[(size_t)ar * lda + k0 + kcA]);
      As[kcA + 0][r] = av.x;
      As[kcA + 1][r] = av.y;
      As[kcA + 2][r] = av.z;
      As[kcA + 3][r] = av.w;
    }
    float4 bv = *reinterpret_cast<const float4*>(&Bm[(size_t)(k0 + rB) * ldb + n0 + cB]);
    *reinterpret_cast<float4*>(&Bs[rB][cB]) = bv;
    __syncthreads();
    #pragma unroll
    for (int kk = 0; kk < GBK; ++kk) {
      float a[8], b[4];
      #pragma unroll
      for (int j = 0; j < 4; ++j) b[j] = Bs[kk][tx * 4 + j];
      #pragma unroll
      for (int i = 0; i < 8; ++i) a[i] = As[kk][ty * 8 + i];
      #pragma unroll
      for (int i = 0; i < 8; ++i)
        #pragma unroll
        for (int j = 0; j < 4; ++j)
          acc[i][j] += a[i] * b[j];
    }
    __syncthreads();
  }

  #pragma unroll
  for (int i = 0; i < 8; ++i) {
    int r = ty * 8 + i;
    if (arow_s[r] < 0) continue;
    int crow = cRowBase + r;
    float4 ov;
    float* po = &C[(size_t)crow * ldc + n0 + tx * 4];
    float vv0 = acc[i][0] + bias[n0 + tx * 4 + 0];
    float vv1 = acc[i][1] + bias[n0 + tx * 4 + 1];
    float vv2 = acc[i][2] + bias[n0 + tx * 4 + 2];
    float vv3 = acc[i][3] + bias[n0 + tx * 4 + 3];
    if (ACT == 1) {
      vv0 = 0.5f * vv0 * (1.0f + erff(vv0 * 0.70710678118654752f));
      vv1 = 0.5f * vv1 * (1.0f + erff(vv1 * 0.70710678118654752f));
      vv2 = 0.5f * vv2 * (1.0f + erff(vv2 * 0.70710678118654752f));
      vv3 = 0.5f * vv3 * (1.0f + erff(vv3 * 0.70710678118654752f));
    }
    ov.x = vv0; ov.y = vv1; ov.z = vv2; ov.w = vv3;
    *reinterpret_cast<float4*>(po) = ov;
  }
}

// QKV (grid.z selects q/k/v); also reused for the O-projection with grid.z=1.
__global__ __launch_bounds__(256) void qkv_kernel(
    const float* __restrict__ x,
    const float* __restrict__ W0, const float* __restrict__ W1, const float* __restrict__ W2,
    const float* __restrict__ b0, const float* __restrict__ b1, const float* __restrict__ b2,
    float* __restrict__ o0, float* __restrict__ o1, float* __restrict__ o2)
{
  __shared__ int arow_s[GBM];
  const float* W; const float* bb; float* out;
  if (blockIdx.z == 0)      { W = W0; bb = b0; out = o0; }
  else if (blockIdx.z == 1) { W = W1; bb = b1; out = o1; }
  else                      { W = W2; bb = b2; out = o2; }
  int m0 = blockIdx.y * GBM;
  for (int i = threadIdx.x; i < GBM; i += 256) arow_s[i] = m0 + i;
  __syncthreads();
  gemm_body<0>(x, Dm, W, Dm, bb, out, Dm, blockIdx.x * GBN, Dm, m0, arow_s);
}

// Expert GEMM. gatherA=1: A rows via row_token (the h pass); gatherA=0: A rows
// are slots directly (the y pass). grid: (N/GBN, 8, E)
template<int ACT>
__global__ __launch_bounds__(256) void moe_gemm(
    const float* __restrict__ Abase, int lda,
    const float* __restrict__ Bbase, const float* __restrict__ biasBase,
    float* __restrict__ C, int ldc,
    int N, int K,
    const int* __restrict__ counts, const int* __restrict__ offsets,
    const int* __restrict__ row_token, int gatherA)
{
  __shared__ int arow_s[GBM];
  int e = blockIdx.z;
  int cnt = counts[e];
  int off = offsets[e];
  int mt = blockIdx.y;
  if (mt * GBM >= cnt) return;
  for (int i = threadIdx.x; i < GBM; i += 256) {
    int r = mt * GBM + i;
    int a = -1;
    if (r < cnt) {
      int slot = off + r;
      a = gatherA ? row_token[slot] : slot;
    }
    arow_s[i] = a;
  }
  __syncthreads();
  gemm_body<ACT>(Abase, lda, Bbase + (size_t)e * K * N, N, biasBase + (size_t)e * N,
                 C, ldc, blockIdx.x * GBN, K, off + mt * GBM, arow_s);
}

// ---------------- embedding ----------------
__global__ __launch_bounds__(256) void embed_kernel(
    const int* __restrict__ src, const float* __restrict__ tok,
    const float* __restrict__ pos, const float* __restrict__ stepe,
    const float* __restrict__ steps, float* __restrict__ x)
{
  int idx = blockIdx.x * 256 + threadIdx.x;   // < TD
  int t = idx >> 9, d = idx & 511;
  int b = t >> 9, c = t & 511;
  int tk = src[t];
  x[idx] = tok[(size_t)tk * Dm + d] * 22.627416997969522f
         + pos[c * Dm + d] + stepe[d] * steps[b];
}

// ---------------- attention ----------------
__global__ __launch_bounds__(256) void attn_kernel(
    const float* __restrict__ q, const float* __restrict__ kk,
    const float* __restrict__ vv, const int* __restrict__ mask,
    float* __restrict__ o)
{
  constexpr int QT = 16;
  __shared__ float Qs[QT][65];
  __shared__ float KVs[64][65];
  __shared__ float Ss[QT][513];
  __shared__ float red[QT][16];
  __shared__ float rowmax[QT];
  __shared__ float rowsum[QT];
  __shared__ float msk[64];
  int qt = blockIdx.x, h = blockIdx.y, b = blockIdx.z;
  int tid = threadIdx.x;
  int r4 = tid >> 4;
  int c4 = (tid & 15) << 2;
  {
    const float4 qv = *(const float4*)&q[((size_t)(b * Cseq + qt * QT + r4)) * Dm + h * HDm + c4];
    Qs[r4][c4] = qv.x; Qs[r4][c4 + 1] = qv.y; Qs[r4][c4 + 2] = qv.z; Qs[r4][c4 + 3] = qv.w;
  }
  int myq = tid >> 4;
  int kslot = tid & 15;
  for (int kt = 0; kt < 8; ++kt) {
    #pragma unroll
    for (int j = 0; j < 4; ++j) {
      int row = (tid >> 4) + j * 16;
      const float4 kv = *(const float4*)&kk[((size_t)(b * Cseq + kt * 64 + row)) * Dm + h * HDm + c4];
      KVs[row][c4] = kv.x; KVs[row][c4 + 1] = kv.y; KVs[row][c4 + 2] = kv.z; KVs[row][c4 + 3] = kv.w;
    }
    if (tid < 64) msk[tid] = (float)mask[b * Cseq + kt * 64 + tid];
    __syncthreads();
    #pragma unroll
    for (int j = 0; j < 4; ++j) {
      int key = kslot + j * 16;
      float acc = 0.f;
      #pragma unroll
      for (int d = 0; d < 64; ++d) acc += Qs[myq][d] * KVs[key][d];
      float sv = (msk[key] == 0.f) ? -1e10f : acc * 0.125f;
      Ss[myq][kt * 64 + key] = sv;
    }
    __syncthreads();
  }
  // softmax over 512 keys per row
  {
    int rrow = tid >> 4, seg = tid & 15;
    float lm = -1e30f;
    for (int c = seg * 32; c < seg * 32 + 32; ++c) lm = fmaxf(lm, Ss[rrow][c]);
    red[rrow][seg] = lm; __syncthreads();
    if (tid < QT) {
      float m = -1e30f;
      for (int s2 = 0; s2 < 16; ++s2) m = fmaxf(m, red[tid][s2]);
      rowmax[tid] = m;
    }
    __syncthreads();
    float m = rowmax[rrow];
    float ls = 0.f;
    for (int c = seg * 32; c < seg * 32 + 32; ++c) {
      float e2 = expf(Ss[rrow][c] - m);
      Ss[rrow][c] = e2; ls += e2;
    }
    red[rrow][seg] = ls; __syncthreads();
    if (tid < QT) {
      float s2 = 0.f;
      for (int s3 = 0; s3 < 16; ++s3) s2 += red[tid][s3];
      rowsum[tid] = s2;
    }
    __syncthreads();
  }
  // PV
  float acc[4] = {0.f, 0.f, 0.f, 0.f};
  int d0 = tid & 15;
  for (int kt = 0; kt < 8; ++kt) {
    #pragma unroll
    for (int j = 0; j < 4; ++j) {
      int row = (tid >> 4) + j * 16;
      const float4 v4 = *(const float4*)&vv[((size_t)(b * Cseq + kt * 64 + row)) * Dm + h * HDm + c4];
      KVs[row][c4] = v4.x; KVs[row][c4 + 1] = v4.y; KVs[row][c4 + 2] = v4.z; KVs[row][c4 + 3] = v4.w;
    }
    __syncthreads();
    for (int key = 0; key < 64; ++key) {
      float s = Ss[myq][kt * 64 + key];
      #pragma unroll
      for (int j = 0; j < 4; ++j) acc[j] += s * KVs[key][d0 + j * 16];
    }
    __syncthreads();
  }
  float inv = 1.f / rowsum[myq];
  #pragma unroll
  for (int j = 0; j < 4; ++j)
    o[((size_t)(b * Cseq + qt * QT + myq)) * Dm + h * HDm + d0 + j * 16] = acc[j] * inv;
}

// ---------------- residual + layernorm ----------------
__global__ __launch_bounds__(256) void residual_ln(
    float* __restrict__ x, const float* __restrict__ res,
    const float* __restrict__ gg, const float* __restrict__ bb)
{
  __shared__ float sred[256];
  int t = blockIdx.x, tid = threadIdx.x;
  size_t base = (size_t)t * Dm;
  float v0 = x[base + tid] + res[base + tid];
  float v1 = x[base + 256 + tid] + res[base + 256 + tid];
  sred[tid] = v0 + v1; __syncthreads();
  for (int o2 = 128; o2 > 0; o2 >>= 1) { if (tid < o2) sred[tid] += sred[tid + o2]; __syncthreads(); }
  float mean = sred[0] * (1.f / 512.f); __syncthreads();
  float d0 = v0 - mean, d1 = v1 - mean;
  sred[tid] = d0 * d0 + d1 * d1; __syncthreads();
  for (int o2 = 128; o2 > 0; o2 >>= 1) { if (tid < o2) sred[tid] += sred[tid + o2]; __syncthreads(); }
  float inv = rsqrtf(sred[0] * (1.f / 512.f) + 1e-5f);
  x[base + tid]       = d0 * inv * gg[tid]       + bb[tid];
  x[base + 256 + tid] = d1 * inv * gg[256 + tid] + bb[256 + tid];
}

__global__ __launch_bounds__(256) void moe_combine_ln(
    float* __restrict__ x, const float* __restrict__ y,
    const int* __restrict__ slot_of, const float* __restrict__ gw,
    const float* __restrict__ gg, const float* __restrict__ bb)
{
  __shared__ float sred[256];
  int t = blockIdx.x, tid = threadIdx.x;
  size_t base = (size_t)t * Dm;
  int s0 = slot_of[2 * t], s1 = slot_of[2 * t + 1];
  float g0 = gw[2 * t], g1 = gw[2 * t + 1];
  float r0 = g0 * y[(size_t)s0 * Dm + tid]       + g1 * y[(size_t)s1 * Dm + tid];
  float r1 = g0 * y[(size_t)s0 * Dm + 256 + tid] + g1 * y[(size_t)s1 * Dm + 256 + tid];
  float v0 = x[base + tid] + r0;
  float v1 = x[base + 256 + tid] + r1;
  sred[tid] = v0 + v1; __syncthreads();
  for (int o2 = 128; o2 > 0; o2 >>= 1) { if (tid < o2) sred[tid] += sred[tid + o2]; __syncthreads(); }
  float mean = sred[0] * (1.f / 512.f); __syncthreads();
  float d0 = v0 - mean, d1 = v1 - mean;
  sred[tid] = d0 * d0 + d1 * d1; __syncthreads();
  for (int o2 = 128; o2 > 0; o2 >>= 1) { if (tid < o2) sred[tid] += sred[tid + o2]; __syncthreads(); }
  float inv = rsqrtf(sred[0] * (1.f / 512.f) + 1e-5f);
  x[base + tid]       = d0 * inv * gg[tid]       + bb[tid];
  x[base + 256 + tid] = d1 * inv * gg[256 + tid] + bb[256 + tid];
}

// ---------------- router / MoE bookkeeping ----------------
__global__ void zero_kernel(int* __restrict__ counts, int* __restrict__ counts2)
{
  if (threadIdx.x < Eexp) { counts[threadIdx.x] = 0; counts2[threadIdx.x] = 0; }
}

__global__ __launch_bounds__(256) void router_kernel(
    const float* __restrict__ x, const float* __restrict__ rW,
    const float* __restrict__ rb, int* __restrict__ topi,
    float* __restrict__ gw, int* __restrict__ counts)
{
  int wave = threadIdx.x >> 6, lane = threadIdx.x & 63;
  int t = blockIdx.x * 4 + wave;
  float tot[Eexp] = {};
  size_t base = (size_t)t * Dm;
  for (int d = lane; d < Dm; d += 64) {
    float xv = x[base + d];
    const float* r = rW + d * Eexp;
    #pragma unroll
    for (int e = 0; e < Eexp; ++e) tot[e] += xv * r[e];
  }
  #pragma unroll
  for (int off = 32; off > 0; off >>= 1) {
    #pragma unroll
    for (int e = 0; e < Eexp; ++e) tot[e] += __shfl_down(tot[e], off, 64);
  }
  if (lane == 0) {
    float best = -1e30f; int bi = 0;
    #pragma unroll
    for (int e = 0; e < Eexp; ++e) {
      float v = tot[e] + rb[e]; tot[e] = v;
      if (v > best) { best = v; bi = e; }
    }
    float b2 = -1e30f; int bi2 = 0;
    #pragma unroll
    for (int e = 0; e < Eexp; ++e) {
      if (e == bi) continue;
      if (tot[e] > b2) { b2 = tot[e]; bi2 = e; }
    }
    float e1 = expf(b2 - best);
    float invs = 1.f / (1.f + e1);
    topi[2 * t] = bi; topi[2 * t + 1] = bi2;
    gw[2 * t] = invs; gw[2 * t + 1] = e1 * invs;
    atomicAdd(&counts[bi], 1); atomicAdd(&counts[bi2], 1);
  }
}

__global__ void offsets_kernel(const int* __restrict__ counts, int* __restrict__ offsets,
                               int* __restrict__ counts2)
{
  if (threadIdx.x == 0) {
    int acc = 0;
    for (int e = 0; e < Eexp; ++e) { offsets[e] = acc; acc += counts[e]; }
  }
  if (threadIdx.x < Eexp) counts2[threadIdx.x] = 0;
}

__global__ __launch_bounds__(256) void assign_kernel(
    const int* __restrict__ topi, const int* __restrict__ offsets,
    int* __restrict__ counts2, int* __restrict__ row_token, int* __restrict__ slot_of)
{
  int t = blockIdx.x * blockDim.x + threadIdx.x;
  if (t >= Ttok) return;
  for (int kk = 0; kk < Ktop; ++kk) {
    int e = topi[2 * t + kk];
    int pos = atomicAdd(&counts2[e], 1);
    int slot = offsets[e] + pos;
    row_token[slot] = t;
    slot_of[2 * t + kk] = slot;
  }
}

// ---------------- host launch ----------------
extern "C" void kernel_launch(void* const* d_in, const int* in_sizes, int n_in,
                              void* d_out, int out_size, void* d_ws, size_t ws_size,
                              hipStream_t stream)
{
  const int*   src      = (const int*)d_in[0];
  const int*   mask     = (const int*)d_in[1];
  const float* steps    = (const float*)d_in[2];
  const float* tok_emb  = (const float*)d_in[3];
  const float* pos_emb  = (const float*)d_in[4];
  const float* step_emb = (const float*)d_in[5];
  const float* attn_g   = (const float*)d_in[6];
  const float* attn_b   = (const float*)d_in[7];
  const float* ff_g     = (const float*)d_in[8];
  const float* ff_b     = (const float*)d_in[9];
  const float* Wq       = (const float*)d_in[10];
  const float* Wk       = (const float*)d_in[11];
  const float* Wv       = (const float*)d_in[12];
  const float* Wo       = (const float*)d_in[13];
  const float* bq       = (const float*)d_in[14];
  const float* bk       = (const float*)d_in[15];
  const float* bv       = (const float*)d_in[16];
  const float* bo       = (const float*)d_in[17];
  const float* rW       = (const float*)d_in[18];
  const float* rb       = (const float*)d_in[19];
  const float* eW1      = (const float*)d_in[20];
  const float* eb1      = (const float*)d_in[21];
  const float* eW2      = (const float*)d_in[22];
  const float* eb2      = (const float*)d_in[23];

  float* x = (float*)d_out;             // activations live in d_out throughout

  float* ws   = (float*)d_ws;
  float* q    = ws;
  float* kbuf = q + TD;
  float* vbuf = kbuf + TD;
  float* attno = vbuf + TD;
  float* projo = attno + TD;
  float* h    = projo + TD;             // 2048 x 2048
  float* y    = h + (size_t)2048 * FFm; // 2048 x 512
  float* gatesw = y + (size_t)2048 * Dm;
  int* topi      = (int*)(gatesw + 2048);
  int* slot_of   = topi + 2048;
  int* row_token = slot_of + 2048;
  int* counts    = row_token + 2048;
  int* counts2   = counts + Eexp;
  int* offsets   = counts2 + Eexp;

  embed_kernel<<<TD / 256, 256, 0, stream>>>(src, tok_emb, pos_emb, step_emb, steps, x);

  for (int l = 0; l < Lnum; ++l) {
    const float* Wq_l = Wq + (size_t)l * Dm * Dm;
    const float* Wk_l = Wk + (size_t)l * Dm * Dm;
    const float* Wv_l = Wv + (size_t)l * Dm * Dm;
    const float* Wo_l = Wo + (size_t)l * Dm * Dm;
    const float* bq_l = bq + (size_t)l * Dm;
    const float* bk_l = bk + (size_t)l * Dm;
    const float* bv_l = bv + (size_t)l * Dm;
    const float* bo_l = bo + (size_t)l * Dm;
    const float* ag_l = attn_g + (size_t)l * Dm;
    const float* ab_l = attn_b + (size_t)l * Dm;
    const float* fg_l = ff_g + (size_t)l * Dm;
    const float* fb_l = ff_b + (size_t)l * Dm;
    const float* rW_l = rW + (size_t)l * Dm * Eexp;
    const float* rb_l = rb + (size_t)l * Eexp;
    const float* eW1_l = eW1 + (size_t)l * Eexp * Dm * FFm;
    const float* eb1_l = eb1 + (size_t)l * Eexp * FFm;
    const float* eW2_l = eW2 + (size_t)l * Eexp * FFm * Dm;
    const float* eb2_l = eb2 + (size_t)l * Eexp * Dm;

    qkv_kernel<<<dim3(Dm / GBN, Ttok / GBM, 3), 256, 0, stream>>>(
        x, Wq_l, Wk_l, Wv_l, bq_l, bk_l, bv_l, q, kbuf, vbuf);

    attn_kernel<<<dim3(Cseq / 16, NHd, Bsz), 256, 0, stream>>>(q, kbuf, vbuf, mask, attno);

    qkv_kernel<<<dim3(Dm / GBN, Ttok / GBM, 1), 256, 0, stream>>>(
        attno, Wo_l, Wo_l, Wo_l, bo_l, bo_l, bo_l, projo, projo, projo);

    residual_ln<<<Ttok, 256, 0, stream>>>(x, projo, ag_l, ab_l);

    zero_kernel<<<1, 64, 0, stream>>>(counts, counts2);
    router_kernel<<<Ttok / 4, 256, 0, stream>>>(x, rW_l, rb_l, topi, gatesw, counts);
    offsets_kernel<<<1, 64, 0, stream>>>(counts, offsets, counts2);
    assign_kernel<<<Ttok / 256, 256, 0, stream>>>(topi, offsets, counts2, row_token, slot_of);

    moe_gemm<1><<<dim3(FFm / GBN, Ttok / GBM, Eexp), 256, 0, stream>>>(
        x, Dm, eW1_l, eb1_l, h, FFm, FFm, Dm, counts, offsets, row_token, 1);

    moe_gemm<0><<<dim3(Dm / GBN, Ttok / GBM, Eexp), 256, 0, stream>>>(
        h, FFm, eW2_l, eb2_l, y, Dm, Dm, FFm, counts, offsets, row_token, 0);

    moe_combine_ln<<<Ttok, 256, 0, stream>>>(x, y, slot_of, gatesw, fg_l, fb_l);
  }
}

// Round 2
// 862.863 us; speedup vs baseline: 1.7142x; 1.7142x over previous
//
#include <hip/hip_runtime.h>
#include <hip/hip_bf16.h>
#include <math.h>

// Problem constants
#define Bsz 2
#define Cseq 512
#define Dm 512
#define NHd 8
#define HDm 64
#define Eexp 8
#define Ktop 2
#define FFm 2048
#define Lnum 2
#define Ttok (Bsz*Cseq)          // 1024
#define TD (Ttok*Dm)             // 524288

typedef unsigned short u16;
typedef unsigned int u32;
typedef __attribute__((ext_vector_type(8))) short short8;
typedef __attribute__((ext_vector_type(4))) float f32x4;

__device__ __forceinline__ float b2f(u16 b) { return __uint_as_float(((u32)b) << 16); }
__device__ __forceinline__ u16 f2b(float f) {
  __hip_bfloat16 h = __float2bfloat16(f);
  return *reinterpret_cast<u16*>(&h);
}

__device__ __forceinline__ void gload16(const u16* g, u16* l) {
  __builtin_amdgcn_global_load_lds(
      (const __attribute__((address_space(1))) u32*)(const void*)g,
      (__attribute__((address_space(3))) u32*)(void*)l, 16, 0, 0);
}

// ================= MFMA GEMM core =================
// C[128,128] tile of A[M,K](bf16, rows gathered via arow_s) @ WT[N,K](bf16)^T.
// LDS layout per operand tile: [4 kblk][128 row][8 bf16] (8 KB).
// 256 threads = 4 waves in 2x2; each wave does 64x64 via 4x4 16x16x32 MFMAs.
template<int DUMMY>
__device__ __forceinline__ void gemm_core(
    const u16* __restrict__ A, int lda,
    const u16* __restrict__ WT, int K, int n0,
    const int* __restrict__ arow_s,
    u16* __restrict__ Als, u16* __restrict__ Bls,
    f32x4 acc[4][4])
{
  const int tid = threadIdx.x;
  const int w = tid >> 6;
  const int lane = tid & 63;

  // staging descriptors (byte offsets into 8KB LDS tile, 16B per thread, x2)
  const int o0 = tid * 16, o1 = o0 + 4096;
  const int ka0 = o0 >> 11, ra0 = (o0 & 2047) >> 4;
  const int ka1 = o1 >> 11, ra1 = (o1 & 2047) >> 4;
  int ta0 = arow_s[ra0]; if (ta0 < 0) ta0 = arow_s[0];
  int ta1 = arow_s[ra1]; if (ta1 < 0) ta1 = arow_s[0];
  const u16* pa0 = A + (size_t)ta0 * lda + ka0 * 8;
  const u16* pa1 = A + (size_t)ta1 * lda + ka1 * 8;
  const u16* pb0 = WT + (size_t)(n0 + ra0) * K + ka0 * 8;
  const u16* pb1 = WT + (size_t)(n0 + ra1) * K + ka1 * 8;
  u16* la0 = Als + w * 512;          // wave-uniform LDS bases (bytes: w*1024)
  u16* la1 = Als + w * 512 + 2048;   // +4096B
  u16* lb0 = Bls + w * 512;
  u16* lb1 = Bls + w * 512 + 2048;

  const int wm = w >> 1, wn = w & 1;
  const int lrow = lane & 15, lk = lane >> 4;
  const u16* aRd = Als + lk * 1024 + (wm * 64 + lrow) * 8;
  const u16* bRd = Bls + lk * 1024 + (wn * 64 + lrow) * 8;

  for (int k0 = 0; k0 < K; k0 += 32) {
    gload16(pa0 + k0, la0);
    gload16(pa1 + k0, la1);
    gload16(pb0 + k0, lb0);
    gload16(pb1 + k0, lb1);
    __syncthreads();   // compiler emits vmcnt(0) drain before barrier
    short8 af[4], bfr[4];
    #pragma unroll
    for (int m = 0; m < 4; ++m) af[m] = *reinterpret_cast<const short8*>(aRd + m * 128);
    #pragma unroll
    for (int n = 0; n < 4; ++n) bfr[n] = *reinterpret_cast<const short8*>(bRd + n * 128);
    #pragma unroll
    for (int m = 0; m < 4; ++m)
      #pragma unroll
      for (int n = 0; n < 4; ++n)
        acc[m][n] = __builtin_amdgcn_mfma_f32_16x16x32_bf16(af[m], bfr[n], acc[m][n], 0, 0, 0);
    __syncthreads();
  }
}

// Generic MFMA GEMM. mode 0: dense rows (A row = C row = m0+r, Mtot bound).
// mode 1: A rows gathered via row_token (MoE h pass), C row = slot.
// mode 2: A rows = slots (MoE y pass), C row = slot.
template<int ACT, int OUTBF>
__global__ __launch_bounds__(256) void mfma_gemm(
    const u16* __restrict__ A, int lda,
    const u16* __restrict__ WTbase, size_t wstride, int K, int N,
    const float* __restrict__ biasBase, int bstride,
    void* __restrict__ Cout, int ldc,
    int Mtot, int mode,
    const int* __restrict__ counts, const int* __restrict__ offsets,
    const int* __restrict__ row_token)
{
  __shared__ u16 Als[4096];
  __shared__ u16 Bls[4096];
  __shared__ int arow_s[128];
  const int e = blockIdx.z, mt = blockIdx.y;
  const int cnt = (mode == 0) ? Mtot : counts[e];
  const int off = (mode == 0) ? 0 : offsets[e];
  if (mt * 128 >= cnt) return;
  for (int i = threadIdx.x; i < 128; i += 256) {
    int r = mt * 128 + i, a = -1;
    if (r < cnt) a = (mode == 0) ? r : (mode == 1 ? row_token[off + r] : off + r);
    arow_s[i] = a;
  }
  __syncthreads();
  f32x4 acc[4][4];
  #pragma unroll
  for (int m = 0; m < 4; ++m)
    #pragma unroll
    for (int n = 0; n < 4; ++n) acc[m][n] = f32x4{0.f, 0.f, 0.f, 0.f};

  const int n0 = blockIdx.x * 128;
  gemm_core<0>(A, lda, WTbase + (size_t)e * wstride, K, n0, arow_s, Als, Bls, acc);

  const float* bias = biasBase + (size_t)e * bstride;
  const int tid = threadIdx.x, w = tid >> 6, lane = tid & 63;
  const int wm = w >> 1, wn = w & 1, lrow = lane & 15, lk = lane >> 4;
  #pragma unroll
  for (int m = 0; m < 4; ++m) {
    #pragma unroll
    for (int j = 0; j < 4; ++j) {
      int rl = wm * 64 + m * 16 + lk * 4 + j;
      if (arow_s[rl] < 0) continue;
      int crow = off + mt * 128 + rl;
      #pragma unroll
      for (int n = 0; n < 4; ++n) {
        int cl = wn * 64 + n * 16 + lrow;
        float v = acc[m][n][j] + bias[n0 + cl];
        if (ACT == 1) v = 0.5f * v * (1.0f + erff(v * 0.70710678118654752f));
        if (OUTBF) ((u16*)Cout)[(size_t)crow * ldc + n0 + cl] = f2b(v);
        else       ((float*)Cout)[(size_t)crow * ldc + n0 + cl] = v;
      }
    }
  }
}

// Fused QKV GEMM: WT = wqkvT [1536][512]; n-tile selects q/k/v output.
__global__ __launch_bounds__(256) void mfma_qkv(
    const u16* __restrict__ xb, const u16* __restrict__ wqkvT,
    const float* __restrict__ bq, const float* __restrict__ bk, const float* __restrict__ bv,
    u16* __restrict__ qo, u16* __restrict__ ko, u16* __restrict__ vo)
{
  __shared__ u16 Als[4096];
  __shared__ u16 Bls[4096];
  __shared__ int arow_s[128];
  const int mt = blockIdx.y, nt = blockIdx.x;
  for (int i = threadIdx.x; i < 128; i += 256) arow_s[i] = mt * 128 + i;
  __syncthreads();
  f32x4 acc[4][4];
  #pragma unroll
  for (int m = 0; m < 4; ++m)
    #pragma unroll
    for (int n = 0; n < 4; ++n) acc[m][n] = f32x4{0.f, 0.f, 0.f, 0.f};
  gemm_core<0>(xb, Dm, wqkvT, Dm, nt * 128, arow_s, Als, Bls, acc);

  const int which = nt >> 2;
  u16* outp = which == 0 ? qo : (which == 1 ? ko : vo);
  const float* bp = which == 0 ? bq : (which == 1 ? bk : bv);
  const int colbase = (nt & 3) * 128;
  const int tid = threadIdx.x, w = tid >> 6, lane = tid & 63;
  const int wm = w >> 1, wn = w & 1, lrow = lane & 15, lk = lane >> 4;
  #pragma unroll
  for (int m = 0; m < 4; ++m) {
    #pragma unroll
    for (int j = 0; j < 4; ++j) {
      int row = mt * 128 + wm * 64 + m * 16 + lk * 4 + j;
      #pragma unroll
      for (int n = 0; n < 4; ++n) {
        int col = colbase + wn * 64 + n * 16 + lrow;
        outp[(size_t)row * Dm + col] = f2b(acc[m][n][j] + bp[col]);
      }
    }
  }
}

// ============ weight transpose + fp32->bf16 convert (per layer) ============
// z: 0-2 Wq/Wk/Wv -> wqkvT; 3 Wo -> woT; 4-11 eW1 -> w1T; 12-19 eW2 -> w2T
__global__ __launch_bounds__(256) void transpose_cvt(
    const float* __restrict__ Wq, const float* __restrict__ Wk,
    const float* __restrict__ Wv, const float* __restrict__ Wo,
    const float* __restrict__ eW1, const float* __restrict__ eW2,
    u16* __restrict__ qkvT, u16* __restrict__ woT,
    u16* __restrict__ w1T, u16* __restrict__ w2T, int layer)
{
  const int z = blockIdx.z;
  const float* src; u16* dst; int K, N;
  if (z < 3) {
    src = (z == 0 ? Wq : (z == 1 ? Wk : Wv)) + (size_t)layer * Dm * Dm;
    K = Dm; N = Dm; dst = qkvT + (size_t)z * Dm * Dm;
  } else if (z < 4) {
    src = Wo + (size_t)layer * Dm * Dm; K = Dm; N = Dm; dst = woT;
  } else if (z < 12) {
    int ex = z - 4;
    src = eW1 + ((size_t)layer * Eexp + ex) * Dm * FFm;
    K = Dm; N = FFm; dst = w1T + (size_t)ex * Dm * FFm;
  } else {
    int ex = z - 12;
    src = eW2 + ((size_t)layer * Eexp + ex) * FFm * Dm;
    K = FFm; N = Dm; dst = w2T + (size_t)ex * FFm * Dm;
  }
  const int n0 = blockIdx.x * 64, k0 = blockIdx.y * 64;
  if (n0 >= N || k0 >= K) return;
  __shared__ float tile[64][65];
  const int c = (threadIdx.x & 15) * 4, r = threadIdx.x >> 4;
  #pragma unroll
  for (int i = 0; i < 4; ++i) {
    float4 v4 = *reinterpret_cast<const float4*>(&src[(size_t)(k0 + r + i * 16) * N + n0 + c]);
    tile[r + i * 16][c + 0] = v4.x; tile[r + i * 16][c + 1] = v4.y;
    tile[r + i * 16][c + 2] = v4.z; tile[r + i * 16][c + 3] = v4.w;
  }
  __syncthreads();
  #pragma unroll
  for (int i = 0; i < 4; ++i) {
    int n = n0 + r + i * 16;
    u32 lo = (u32)f2b(tile[c + 0][r + i * 16]) | ((u32)f2b(tile[c + 1][r + i * 16]) << 16);
    u32 hi = (u32)f2b(tile[c + 2][r + i * 16]) | ((u32)f2b(tile[c + 3][r + i * 16]) << 16);
    uint2 pk; pk.x = lo; pk.y = hi;
    *reinterpret_cast<uint2*>(&dst[(size_t)n * K + k0 + c]) = pk;
  }
}

// ---------------- embedding ----------------
__global__ __launch_bounds__(256) void embed_kernel(
    const int* __restrict__ src, const float* __restrict__ tok,
    const float* __restrict__ pos, const float* __restrict__ stepe,
    const float* __restrict__ steps, float* __restrict__ x, u16* __restrict__ xb)
{
  int idx = blockIdx.x * 256 + threadIdx.x;   // < TD
  int t = idx >> 9, d = idx & 511;
  int b = t >> 9, c = t & 511;
  int tk = src[t];
  float v = tok[(size_t)tk * Dm + d] * 22.627416997969522f
          + pos[c * Dm + d] + stepe[d] * steps[b];
  x[idx] = v;
  xb[idx] = f2b(v);
}

// ---------------- attention (fp32 VALU, bf16 in/out) ----------------
__global__ __launch_bounds__(256) void attn_kernel(
    const u16* __restrict__ q, const u16* __restrict__ kk,
    const u16* __restrict__ vv, const int* __restrict__ mask,
    u16* __restrict__ o)
{
  constexpr int QT = 16;
  __shared__ float Qs[QT][65];
  __shared__ float KVs[64][65];
  __shared__ float Ss[QT][513];
  __shared__ float red[QT][16];
  __shared__ float rowmax[QT];
  __shared__ float rowsum[QT];
  __shared__ float msk[64];
  int qt = blockIdx.x, h = blockIdx.y, b = blockIdx.z;
  int tid = threadIdx.x;
  int r4 = tid >> 4;
  int c4 = (tid & 15) << 2;
  {
    uint2 u = *(const uint2*)&q[((size_t)(b * Cseq + qt * QT + r4)) * Dm + h * HDm + c4];
    Qs[r4][c4 + 0] = b2f((u16)(u.x & 0xffff)); Qs[r4][c4 + 1] = b2f((u16)(u.x >> 16));
    Qs[r4][c4 + 2] = b2f((u16)(u.y & 0xffff)); Qs[r4][c4 + 3] = b2f((u16)(u.y >> 16));
  }
  int myq = tid >> 4;
  int kslot = tid & 15;
  for (int kt = 0; kt < 8; ++kt) {
    #pragma unroll
    for (int j = 0; j < 4; ++j) {
      int row = (tid >> 4) + j * 16;
      uint2 u = *(const uint2*)&kk[((size_t)(b * Cseq + kt * 64 + row)) * Dm + h * HDm + c4];
      KVs[row][c4 + 0] = b2f((u16)(u.x & 0xffff)); KVs[row][c4 + 1] = b2f((u16)(u.x >> 16));
      KVs[row][c4 + 2] = b2f((u16)(u.y & 0xffff)); KVs[row][c4 + 3] = b2f((u16)(u.y >> 16));
    }
    if (tid < 64) msk[tid] = (float)mask[b * Cseq + kt * 64 + tid];
    __syncthreads();
    #pragma unroll
    for (int j = 0; j < 4; ++j) {
      int key = kslot + j * 16;
      float acc = 0.f;
      #pragma unroll
      for (int d = 0; d < 64; ++d) acc += Qs[myq][d] * KVs[key][d];
      float sv = (msk[key] == 0.f) ? -1e10f : acc * 0.125f;
      Ss[myq][kt * 64 + key] = sv;
    }
    __syncthreads();
  }
  {
    int rrow = tid >> 4, seg = tid & 15;
    float lm = -1e30f;
    for (int c = seg * 32; c < seg * 32 + 32; ++c) lm = fmaxf(lm, Ss[rrow][c]);
    red[rrow][seg] = lm; __syncthreads();
    if (tid < QT) {
      float m = -1e30f;
      for (int s2 = 0; s2 < 16; ++s2) m = fmaxf(m, red[tid][s2]);
      rowmax[tid] = m;
    }
    __syncthreads();
    float m = rowmax[rrow];
    float ls = 0.f;
    for (int c = seg * 32; c < seg * 32 + 32; ++c) {
      float e2 = expf(Ss[rrow][c] - m);
      Ss[rrow][c] = e2; ls += e2;
    }
    red[rrow][seg] = ls; __syncthreads();
    if (tid < QT) {
      float s2 = 0.f;
      for (int s3 = 0; s3 < 16; ++s3) s2 += red[tid][s3];
      rowsum[tid] = s2;
    }
    __syncthreads();
  }
  float acc[4] = {0.f, 0.f, 0.f, 0.f};
  int d0 = tid & 15;
  for (int kt = 0; kt < 8; ++kt) {
    #pragma unroll
    for (int j = 0; j < 4; ++j) {
      int row = (tid >> 4) + j * 16;
      uint2 u = *(const uint2*)&vv[((size_t)(b * Cseq + kt * 64 + row)) * Dm + h * HDm + c4];
      KVs[row][c4 + 0] = b2f((u16)(u.x & 0xffff)); KVs[row][c4 + 1] = b2f((u16)(u.x >> 16));
      KVs[row][c4 + 2] = b2f((u16)(u.y & 0xffff)); KVs[row][c4 + 3] = b2f((u16)(u.y >> 16));
    }
    __syncthreads();
    for (int key = 0; key < 64; ++key) {
      float s = Ss[myq][kt * 64 + key];
      #pragma unroll
      for (int j = 0; j < 4; ++j) acc[j] += s * KVs[key][d0 + j * 16];
    }
    __syncthreads();
  }
  float inv = 1.f / rowsum[myq];
  #pragma unroll
  for (int j = 0; j < 4; ++j)
    o[((size_t)(b * Cseq + qt * QT + myq)) * Dm + h * HDm + d0 + j * 16] = f2b(acc[j] * inv);
}

// ---------------- residual + layernorm (emit fp32 x and bf16 xb) ----------------
__global__ __launch_bounds__(256) void residual_ln(
    float* __restrict__ x, const float* __restrict__ res,
    const float* __restrict__ gg, const float* __restrict__ bb, u16* __restrict__ xb)
{
  __shared__ float sred[256];
  int t = blockIdx.x, tid = threadIdx.x;
  size_t base = (size_t)t * Dm;
  float v0 = x[base + tid] + res[base + tid];
  float v1 = x[base + 256 + tid] + res[base + 256 + tid];
  sred[tid] = v0 + v1; __syncthreads();
  for (int o2 = 128; o2 > 0; o2 >>= 1) { if (tid < o2) sred[tid] += sred[tid + o2]; __syncthreads(); }
  float mean = sred[0] * (1.f / 512.f); __syncthreads();
  float d0 = v0 - mean, d1 = v1 - mean;
  sred[tid] = d0 * d0 + d1 * d1; __syncthreads();
  for (int o2 = 128; o2 > 0; o2 >>= 1) { if (tid < o2) sred[tid] += sred[tid + o2]; __syncthreads(); }
  float inv = rsqrtf(sred[0] * (1.f / 512.f) + 1e-5f);
  float o0 = d0 * inv * gg[tid] + bb[tid];
  float o1 = d1 * inv * gg[256 + tid] + bb[256 + tid];
  x[base + tid] = o0; x[base + 256 + tid] = o1;
  xb[base + tid] = f2b(o0); xb[base + 256 + tid] = f2b(o1);
}

__global__ __launch_bounds__(256) void moe_combine_ln(
    float* __restrict__ x, const float* __restrict__ y,
    const int* __restrict__ slot_of, const float* __restrict__ gw,
    const float* __restrict__ gg, const float* __restrict__ bb, u16* __restrict__ xb)
{
  __shared__ float sred[256];
  int t = blockIdx.x, tid = threadIdx.x;
  size_t base = (size_t)t * Dm;
  int s0 = slot_of[2 * t], s1 = slot_of[2 * t + 1];
  float g0 = gw[2 * t], g1 = gw[2 * t + 1];
  float r0 = g0 * y[(size_t)s0 * Dm + tid]       + g1 * y[(size_t)s1 * Dm + tid];
  float r1 = g0 * y[(size_t)s0 * Dm + 256 + tid] + g1 * y[(size_t)s1 * Dm + 256 + tid];
  float v0 = x[base + tid] + r0;
  float v1 = x[base + 256 + tid] + r1;
  sred[tid] = v0 + v1; __syncthreads();
  for (int o2 = 128; o2 > 0; o2 >>= 1) { if (tid < o2) sred[tid] += sred[tid + o2]; __syncthreads(); }
  float mean = sred[0] * (1.f / 512.f); __syncthreads();
  float d0 = v0 - mean, d1 = v1 - mean;
  sred[tid] = d0 * d0 + d1 * d1; __syncthreads();
  for (int o2 = 128; o2 > 0; o2 >>= 1) { if (tid < o2) sred[tid] += sred[tid + o2]; __syncthreads(); }
  float inv = rsqrtf(sred[0] * (1.f / 512.f) + 1e-5f);
  float o0 = d0 * inv * gg[tid] + bb[tid];
  float o1 = d1 * inv * gg[256 + tid] + bb[256 + tid];
  x[base + tid] = o0; x[base + 256 + tid] = o1;
  xb[base + tid] = f2b(o0); xb[base + 256 + tid] = f2b(o1);
}

// ---------------- router / MoE bookkeeping ----------------
__global__ void zero_kernel(int* __restrict__ counts, int* __restrict__ counts2)
{
  if (threadIdx.x < Eexp) { counts[threadIdx.x] = 0; counts2[threadIdx.x] = 0; }
}

__global__ __launch_bounds__(256) void router_kernel(
    const float* __restrict__ x, const float* __restrict__ rW,
    const float* __restrict__ rb, int* __restrict__ topi,
    float* __restrict__ gw, int* __restrict__ counts)
{
  int wave = threadIdx.x >> 6, lane = threadIdx.x & 63;
  int t = blockIdx.x * 4 + wave;
  float tot[Eexp] = {};
  size_t base = (size_t)t * Dm;
  for (int d = lane; d < Dm; d += 64) {
    float xv = x[base + d];
    const float* r = rW + d * Eexp;
    #pragma unroll
    for (int e = 0; e < Eexp; ++e) tot[e] += xv * r[e];
  }
  #pragma unroll
  for (int off = 32; off > 0; off >>= 1) {
    #pragma unroll
    for (int e = 0; e < Eexp; ++e) tot[e] += __shfl_down(tot[e], off, 64);
  }
  if (lane == 0) {
    float best = -1e30f; int bi = 0;
    #pragma unroll
    for (int e = 0; e < Eexp; ++e) {
      float v = tot[e] + rb[e]; tot[e] = v;
      if (v > best) { best = v; bi = e; }
    }
    float b2 = -1e30f; int bi2 = 0;
    #pragma unroll
    for (int e = 0; e < Eexp; ++e) {
      if (e == bi) continue;
      if (tot[e] > b2) { b2 = tot[e]; bi2 = e; }
    }
    float e1 = expf(b2 - best);
    float invs = 1.f / (1.f + e1);
    topi[2 * t] = bi; topi[2 * t + 1] = bi2;
    gw[2 * t] = invs; gw[2 * t + 1] = e1 * invs;
    atomicAdd(&counts[bi], 1); atomicAdd(&counts[bi2], 1);
  }
}

__global__ void offsets_kernel(const int* __restrict__ counts, int* __restrict__ offsets,
                               int* __restrict__ counts2)
{
  if (threadIdx.x == 0) {
    int acc = 0;
    for (int e = 0; e < Eexp; ++e) { offsets[e] = acc; acc += counts[e]; }
  }
  if (threadIdx.x < Eexp) counts2[threadIdx.x] = 0;
}

__global__ __launch_bounds__(256) void assign_kernel(
    const int* __restrict__ topi, const int* __restrict__ offsets,
    int* __restrict__ counts2, int* __restrict__ row_token, int* __restrict__ slot_of)
{
  int t = blockIdx.x * blockDim.x + threadIdx.x;
  if (t >= Ttok) return;
  for (int kk = 0; kk < Ktop; ++kk) {
    int e = topi[2 * t + kk];
    int pos = atomicAdd(&counts2[e], 1);
    int slot = offsets[e] + pos;
    row_token[slot] = t;
    slot_of[2 * t + kk] = slot;
  }
}

// ---------------- host launch ----------------
extern "C" void kernel_launch(void* const* d_in, const int* in_sizes, int n_in,
                              void* d_out, int out_size, void* d_ws, size_t ws_size,
                              hipStream_t stream)
{
  const int*   src      = (const int*)d_in[0];
  const int*   mask     = (const int*)d_in[1];
  const float* steps    = (const float*)d_in[2];
  const float* tok_emb  = (const float*)d_in[3];
  const float* pos_emb  = (const float*)d_in[4];
  const float* step_emb = (const float*)d_in[5];
  const float* attn_g   = (const float*)d_in[6];
  const float* attn_b   = (const float*)d_in[7];
  const float* ff_g     = (const float*)d_in[8];
  const float* ff_b     = (const float*)d_in[9];
  const float* Wq       = (const float*)d_in[10];
  const float* Wk       = (const float*)d_in[11];
  const float* Wv       = (const float*)d_in[12];
  const float* Wo       = (const float*)d_in[13];
  const float* bq       = (const float*)d_in[14];
  const float* bk       = (const float*)d_in[15];
  const float* bv       = (const float*)d_in[16];
  const float* bo       = (const float*)d_in[17];
  const float* rW       = (const float*)d_in[18];
  const float* rb       = (const float*)d_in[19];
  const float* eW1      = (const float*)d_in[20];
  const float* eb1      = (const float*)d_in[21];
  const float* eW2      = (const float*)d_in[22];
  const float* eb2      = (const float*)d_in[23];

  float* x = (float*)d_out;

  char* p = (char*)d_ws;
  auto alloc = [&](size_t bytes) { char* r = p; p += (bytes + 255) & ~(size_t)255; return r; };
  u16* xb     = (u16*)alloc((size_t)TD * 2);
  u16* qb     = (u16*)alloc((size_t)TD * 2);
  u16* kb     = (u16*)alloc((size_t)TD * 2);
  u16* vb     = (u16*)alloc((size_t)TD * 2);
  u16* attnob = (u16*)alloc((size_t)TD * 2);
  float* projo = (float*)alloc((size_t)TD * 4);
  u16* hb     = (u16*)alloc((size_t)2048 * FFm * 2);
  float* yb   = (float*)alloc((size_t)2048 * Dm * 4);
  u16* wqkvT  = (u16*)alloc((size_t)3 * Dm * Dm * 2);
  u16* woT    = (u16*)alloc((size_t)Dm * Dm * 2);
  u16* w1T    = (u16*)alloc((size_t)Eexp * Dm * FFm * 2);
  u16* w2T    = (u16*)alloc((size_t)Eexp * FFm * Dm * 2);
  float* gatesw = (float*)alloc(2048 * 4);
  int* topi      = (int*)alloc(2048 * 4);
  int* slot_of   = (int*)alloc(2048 * 4);
  int* row_token = (int*)alloc(2048 * 4);
  int* counts    = (int*)alloc(64);
  int* counts2   = (int*)alloc(64);
  int* offsets   = (int*)alloc(64);

  embed_kernel<<<TD / 256, 256, 0, stream>>>(src, tok_emb, pos_emb, step_emb, steps, x, xb);

  for (int l = 0; l < Lnum; ++l) {
    const float* bq_l = bq + (size_t)l * Dm;
    const float* bk_l = bk + (size_t)l * Dm;
    const float* bv_l = bv + (size_t)l * Dm;
    const float* bo_l = bo + (size_t)l * Dm;
    const float* ag_l = attn_g + (size_t)l * Dm;
    const float* ab_l = attn_b + (size_t)l * Dm;
    const float* fg_l = ff_g + (size_t)l * Dm;
    const float* fb_l = ff_b + (size_t)l * Dm;
    const float* rW_l = rW + (size_t)l * Dm * Eexp;
    const float* rb_l = rb + (size_t)l * Eexp;
    const float* eb1_l = eb1 + (size_t)l * Eexp * FFm;
    const float* eb2_l = eb2 + (size_t)l * Eexp * Dm;

    transpose_cvt<<<dim3(32, 32, 20), 256, 0, stream>>>(
        Wq, Wk, Wv, Wo, eW1, eW2, wqkvT, woT, w1T, w2T, l);

    mfma_qkv<<<dim3(12, 8), 256, 0, stream>>>(xb, wqkvT, bq_l, bk_l, bv_l, qb, kb, vb);

    attn_kernel<<<dim3(Cseq / 16, NHd, Bsz), 256, 0, stream>>>(qb, kb, vb, mask, attnob);

    mfma_gemm<0, 0><<<dim3(4, 8, 1), 256, 0, stream>>>(
        attnob, Dm, woT, (size_t)0, Dm, Dm, bo_l, 0, projo, Dm,
        Ttok, 0, counts, offsets, row_token);

    residual_ln<<<Ttok, 256, 0, stream>>>(x, projo, ag_l, ab_l, xb);

    zero_kernel<<<1, 64, 0, stream>>>(counts, counts2);
    router_kernel<<<Ttok / 4, 256, 0, stream>>>(x, rW_l, rb_l, topi, gatesw, counts);
    offsets_kernel<<<1, 64, 0, stream>>>(counts, offsets, counts2);
    assign_kernel<<<Ttok / 256, 256, 0, stream>>>(topi, offsets, counts2, row_token, slot_of);

    mfma_gemm<1, 1><<<dim3(16, 8, Eexp), 256, 0, stream>>>(
        xb, Dm, w1T, (size_t)Dm * FFm, Dm, FFm, eb1_l, FFm, hb, FFm,
        0, 1, counts, offsets, row_token);

    mfma_gemm<0, 0><<<dim3(4, 8, Eexp), 256, 0, stream>>>(
        hb, FFm, w2T, (size_t)FFm * Dm, FFm, Dm, eb2_l, Dm, yb, Dm,
        0, 2, counts, offsets, row_token);

    moe_combine_ln<<<Ttok, 256, 0, stream>>>(x, yb, slot_of, gatesw, fg_l, fb_l, xb);
  }
}